// Round 17
// baseline (1720.458 us; speedup 1.0000x reference)
//
#include <hip/hip_runtime.h>
#include <hip/hip_bf16.h>

#define T_STEPS 128
#define BATCH   32
#define IN_DIM  512
#define H_DIM   1024
#define OUT_DIM 8192
#define KH      3072   // (K-1)*H
#define NWG     128    // recurrence WGs (fused grid = 256)
#define SLOT_E  32768  // elements per h slot (1024 k * 32 b)
#define NSLOT   131    // h_t stored at slot 127-t; slots 128..130 = zeros
#define NTILE   512    // 16 mb x 32 nb (256x256 tiles)

typedef __attribute__((ext_vector_type(8))) short short8;
typedef __attribute__((ext_vector_type(4))) float f32x4;

__device__ __forceinline__ unsigned short bf16_rne(float f) {
  unsigned u = __float_as_uint(f);
  unsigned r = (u + 0x7FFFu + ((u >> 16) & 1u)) >> 16;
  return (unsigned short)r;
}

__device__ __forceinline__ void gload_lds16(const void* g, void* l) {
  __builtin_amdgcn_global_load_lds(
      (const __attribute__((address_space(1))) void*)g,
      (__attribute__((address_space(3))) void*)l, 16, 0, 0);
}

// ---------------- Wmo f32 -> bf16 ----------------
__global__ __launch_bounds__(256) void convert_kernel(
    const float* __restrict__ src, unsigned short* __restrict__ dst, int n4) {
  int i = blockIdx.x * blockDim.x + threadIdx.x;
  const int stride = gridDim.x * blockDim.x;
  for (; i < n4; i += stride) {
    float4 v = ((const float4*)src)[i];
    ushort4 o;
    o.x = bf16_rne(v.x); o.y = bf16_rne(v.y);
    o.z = bf16_rne(v.z); o.w = bf16_rne(v.w);
    ((ushort4*)dst)[i] = o;
  }
}

// ---------------- pre[t][j][b] = X@Wxh^T + bias (fp32) ---------------------
__global__ __launch_bounds__(256) void pre_kernel(
    const float* __restrict__ X, const float* __restrict__ Wxh,
    const float* __restrict__ bias, float* __restrict__ preT) {
  __shared__ float xs[32][260];
  const int tid = threadIdx.x;
  const int t  = blockIdx.x >> 4;
  const int jb = blockIdx.x & 15;
  const int b  = tid & 31;
  const int jg = tid >> 5;        // 0..7
  float acc[8];
  #pragma unroll
  for (int i = 0; i < 8; ++i) acc[i] = 0.f;

  for (int kc = 0; kc < 2; ++kc) {
    __syncthreads();
    #pragma unroll
    for (int v = tid; v < 2048; v += 256) {
      int br = v >> 6, i4 = v & 63;
      float4 x4 = *(const float4*)(X + (size_t)t*(BATCH*IN_DIM) + (size_t)br*IN_DIM + kc*256 + i4*4);
      *(float4*)&xs[br][i4*4] = x4;
    }
    __syncthreads();
    for (int i = 0; i < 256; i += 4) {
      const int k = kc*256 + i;
      float4 xv = *(const float4*)&xs[b][i];
      #pragma unroll
      for (int jj = 0; jj < 8; ++jj) {
        const int j = jb*64 + jg + jj*8;
        float4 w4 = *(const float4*)(Wxh + (size_t)j*IN_DIM + k);
        acc[jj] += xv.x*w4.x + xv.y*w4.y + xv.z*w4.z + xv.w*w4.w;
      }
    }
  }
  #pragma unroll
  for (int jj = 0; jj < 8; ++jj) {
    const int j = jb*64 + jg + jj*8;
    preT[(size_t)t*(H_DIM*BATCH) + (size_t)j*BATCH + b] = acc[jj] + bias[j];
  }
}

// ---------------- recurrence step (R12 structure; flag at ALL t) -----------
template<int RN, int RD1, int RD2>
__device__ __forceinline__ void do_step(
    const int t, const int tid, const int wg, const int j0,
    const int lane, const int wv,
    const short8* __restrict__ wf, const short8* __restrict__ hi8,
    const short8* __restrict__ lo8, const float* __restrict__ preT,
    unsigned short* __restrict__ hHi, unsigned short* __restrict__ hLo,
    int* __restrict__ grp, int* __restrict__ rootcnt, int* __restrict__ rootrep,
    short8 (&Rh0)[3][4], short8 (&Rh1)[3][4],
    short8 (&Rl0)[3][4], short8 (&Rl1)[3][4],
    float (*red)[16][33],
    unsigned short (*hpk_hi)[8], unsigned short (*hpk_lo)[8]) {
  f32x4 a0h = {}, a0l = {}, a1h = {}, a1l = {};

  // ---- phase A: dk1 + dk2 from registers (no memory) ----
  #pragma unroll
  for (int i = 0; i < 4; ++i) {
    const int ks = 32 + wv*4 + i;
    const short8 af = wf[ks*64 + lane];
    a0h = __builtin_amdgcn_mfma_f32_16x16x32_bf16(af, Rh0[RD1][i], a0h, 0, 0, 0);
    a1h = __builtin_amdgcn_mfma_f32_16x16x32_bf16(af, Rh1[RD1][i], a1h, 0, 0, 0);
    a0l = __builtin_amdgcn_mfma_f32_16x16x32_bf16(af, Rl0[RD1][i], a0l, 0, 0, 0);
    a1l = __builtin_amdgcn_mfma_f32_16x16x32_bf16(af, Rl1[RD1][i], a1l, 0, 0, 0);
  }
  #pragma unroll
  for (int i = 0; i < 4; ++i) {
    const int ks = 64 + wv*4 + i;
    const short8 af = wf[ks*64 + lane];
    a0h = __builtin_amdgcn_mfma_f32_16x16x32_bf16(af, Rh0[RD2][i], a0h, 0, 0, 0);
    a1h = __builtin_amdgcn_mfma_f32_16x16x32_bf16(af, Rh1[RD2][i], a1h, 0, 0, 0);
    a0l = __builtin_amdgcn_mfma_f32_16x16x32_bf16(af, Rl0[RD2][i], a0l, 0, 0, 0);
    a1l = __builtin_amdgcn_mfma_f32_16x16x32_bf16(af, Rl1[RD2][i], a1l, 0, 0, 0);
  }

  // ---- prefetch pre (off the post-reduce critical path) ----
  float upre = 0.f;
  if (tid < 256)
    upre = preT[(size_t)t*(H_DIM*BATCH) + (size_t)(j0 + (tid >> 5))*BATCH + (tid & 31)];

  // ---- wait for h_{t-1}: tid0 polls its replica line, barrier broadcasts --
  if (t > 0) {
    if (tid == 0) {
      while (!__hip_atomic_load(&rootrep[(((t-1) << 3) + (wg & 7)) << 4],
                                __ATOMIC_RELAXED, __HIP_MEMORY_SCOPE_AGENT))
        __builtin_amdgcn_s_sleep(2);
    }
    __syncthreads();
    asm volatile("" ::: "memory");   // no hoisting of slot loads above poll
  }

  // ---- load fresh dk0 slot (h_{t-1}) into set RN ----
  {
    const size_t sb = (size_t)(128 - t) * 4096;   // slot base, 16B units
    #pragma unroll
    for (int i = 0; i < 4; ++i) {
      const int ks = wv*4 + i;
      const size_t bidx = sb + (size_t)ks*128 + (size_t)(lane >> 4)*32 + (lane & 15);
      Rh0[RN][i] = hi8[bidx];
      Rh1[RN][i] = hi8[bidx + 16];
      Rl0[RN][i] = lo8[bidx];
      Rl1[RN][i] = lo8[bidx + 16];
    }
  }
  // ---- phase C: dk0 MFMA ----
  #pragma unroll
  for (int i = 0; i < 4; ++i) {
    const int ks = wv*4 + i;
    const short8 af = wf[ks*64 + lane];
    a0h = __builtin_amdgcn_mfma_f32_16x16x32_bf16(af, Rh0[RN][i], a0h, 0, 0, 0);
    a1h = __builtin_amdgcn_mfma_f32_16x16x32_bf16(af, Rh1[RN][i], a1h, 0, 0, 0);
    a0l = __builtin_amdgcn_mfma_f32_16x16x32_bf16(af, Rl0[RN][i], a0l, 0, 0, 0);
    a1l = __builtin_amdgcn_mfma_f32_16x16x32_bf16(af, Rl1[RN][i], a1l, 0, 0, 0);
  }

  const f32x4 s0 = a0h + a0l;
  const f32x4 s1 = a1h + a1l;
  const int rr = (lane >> 4) * 4, cc = lane & 15;
  #pragma unroll
  for (int q = 0; q < 4; ++q) {
    red[wv][rr + q][cc]      = s0[q];
    red[wv][rr + q][16 + cc] = s1[q];
  }
  __syncthreads();

  if (tid < 256) {
    const int jj = tid >> 5, b = tid & 31;
    float u = upre;
    #pragma unroll
    for (int w = 0; w < 8; ++w)
      u += red[w][jj][b] + red[w][jj + 8][b];
    const float h = u > 0.f ? 1.0507009873554805f*u
                            : (1.0507009873554805f*1.6732632423543772f)*expm1f(u);
    const unsigned short hh = bf16_rne(h);
    hpk_hi[b][jj] = hh;
    hpk_lo[b][jj] = bf16_rne(h - __uint_as_float((unsigned)hh << 16));
  }
  __syncthreads();

  // ---- wave 0: h stores -> ack -> grp -> rootcnt -> 8 replica stores ----
  if (tid < 32) {
    const int b = tid;
    const size_t base = (size_t)(127 - t)*SLOT_E + (size_t)(j0 >> 3)*256 + (size_t)b*8;
    const unsigned long long h0 = *(const unsigned long long*)&hpk_hi[b][0];
    const unsigned long long h1 = *(const unsigned long long*)&hpk_hi[b][4];
    const unsigned long long l0 = *(const unsigned long long*)&hpk_lo[b][0];
    const unsigned long long l1 = *(const unsigned long long*)&hpk_lo[b][4];
    __hip_atomic_store((unsigned long long*)(hHi + base),     h0, __ATOMIC_RELAXED, __HIP_MEMORY_SCOPE_AGENT);
    __hip_atomic_store((unsigned long long*)(hHi + base) + 1, h1, __ATOMIC_RELAXED, __HIP_MEMORY_SCOPE_AGENT);
    __hip_atomic_store((unsigned long long*)(hLo + base),     l0, __ATOMIC_RELAXED, __HIP_MEMORY_SCOPE_AGENT);
    __hip_atomic_store((unsigned long long*)(hLo + base) + 1, l1, __ATOMIC_RELAXED, __HIP_MEMORY_SCOPE_AGENT);
    asm volatile("s_waitcnt vmcnt(0)" ::: "memory");   // h visible at L3
    if (tid == 0) {
      const int g = wg >> 3;   // 16 groups of 8 WGs, private 64B lines
      if (__hip_atomic_fetch_add(&grp[((t << 4) + g) << 4], 1, __ATOMIC_RELAXED, __HIP_MEMORY_SCOPE_AGENT) == 7) {
        if (__hip_atomic_fetch_add(&rootcnt[t << 4], 1, __ATOMIC_RELAXED, __HIP_MEMORY_SCOPE_AGENT) == 15) {
          #pragma unroll
          for (int r = 0; r < 8; ++r)
            __hip_atomic_store(&rootrep[((t << 3) + r) << 4], 1,
                               __ATOMIC_RELAXED, __HIP_MEMORY_SCOPE_AGENT);
        }
      }
    }
  }
  // no barrier: waves proceed into next step's phase A
}

// ---------------- one 256x256 8-phase gemm tile (R16 body) -----------------
__device__ void gemm_tile256(
    const unsigned short* __restrict__ Ah, const unsigned short* __restrict__ Bm,
    float* __restrict__ C, char* smem, const int tid, const int mb, const int nb) {
  const int lane = tid & 63;
  const int wv = tid >> 6;
  const int wm = wv >> 2;                // 0..1
  const int wn = wv & 3;                 // 0..3
  const int lrow = lane & 15, lhalf = lane >> 4;
  const int srow = tid & 127;
  const int ss0 = tid >> 7;
  int tA[2], bA[2];
  #pragma unroll
  for (int h = 0; h < 2; ++h) {
    const int m = mb*256 + h*128 + srow;
    tA[h] = m >> 5; bA[h] = m & 31;
  }

#define STAGE_A(HALF, BUF, KT) do {                                            \
    _Pragma("unroll")                                                          \
    for (int u = 0; u < 2; ++u) {                                              \
      const int s_ = u*4 + ss0;                                                \
      gload_lds16(Ah + (size_t)(127 - tA[HALF])*SLOT_E                         \
                     + (size_t)((KT)*8 + s_)*256 + bA[HALF]*8,                 \
                  smem + (BUF)*65536 + (HALF)*16384 + u*8192 + tid*16);        \
    } } while (0)

#define STAGE_B(HALF, BUF, KT) do {                                            \
    _Pragma("unroll")                                                          \
    for (int u = 0; u < 2; ++u) {                                              \
      const int s_ = u*4 + ss0;                                                \
      gload_lds16(Bm + (size_t)(nb*256 + (HALF)*128 + srow)*4096               \
                     + (size_t)(KT)*64 + s_*8,                                 \
                  smem + (BUF)*65536 + 32768 + (HALF)*16384 + u*8192 + tid*16);\
    } } while (0)

  short8 aF[4][2], bF[2][2];
  f32x4 acc[8][4] = {};

#define PHASE(BUF, MH, NH, RDA, RDB, STAGE_STMT, DO_VM) do {                   \
    if (RDA) {                                                                 \
      _Pragma("unroll")                                                        \
      for (int mi = 0; mi < 4; ++mi)                                           \
        _Pragma("unroll")                                                      \
        for (int kk = 0; kk < 2; ++kk)                                         \
          aF[mi][kk] = *(const short8*)(smem + (BUF)*65536 + wm*16384          \
              + (kk*4 + lhalf)*2048 + ((MH)*64 + mi*16 + lrow)*16);            \
    }                                                                          \
    if (RDB) {                                                                 \
      _Pragma("unroll")                                                        \
      for (int ni = 0; ni < 2; ++ni)                                           \
        _Pragma("unroll")                                                      \
        for (int kk = 0; kk < 2; ++kk)                                         \
          bF[ni][kk] = *(const short8*)(smem + (BUF)*65536 + 32768             \
              + (wn >> 1)*16384 + (kk*4 + lhalf)*2048                          \
              + ((wn & 1)*64 + (NH)*32 + ni*16 + lrow)*16);                    \
    }                                                                          \
    STAGE_STMT;                                                                \
    __builtin_amdgcn_s_barrier();                                              \
    __builtin_amdgcn_s_setprio(1);                                             \
    _Pragma("unroll")                                                          \
    for (int mi = 0; mi < 4; ++mi)                                             \
      _Pragma("unroll")                                                        \
      for (int ni = 0; ni < 2; ++ni) {                                         \
        acc[(MH)*4+mi][(NH)*2+ni] = __builtin_amdgcn_mfma_f32_16x16x32_bf16(   \
            aF[mi][0], bF[ni][0], acc[(MH)*4+mi][(NH)*2+ni], 0, 0, 0);         \
        acc[(MH)*4+mi][(NH)*2+ni] = __builtin_amdgcn_mfma_f32_16x16x32_bf16(   \
            aF[mi][1], bF[ni][1], acc[(MH)*4+mi][(NH)*2+ni], 0, 0, 0);         \
      }                                                                        \
    __builtin_amdgcn_s_setprio(0);                                             \
    if (DO_VM) asm volatile("s_waitcnt vmcnt(2)" ::: "memory");                \
    __builtin_amdgcn_s_barrier();                                              \
  } while (0)

  // ---- prologue: T0 -> buf0 (4 half-tiles), Ah0(T1) -> buf1 ----
  STAGE_A(0, 0, 0);
  STAGE_B(0, 0, 0);
  STAGE_B(1, 0, 0);
  STAGE_A(1, 0, 0);
  STAGE_A(0, 1, 1);
  asm volatile("s_waitcnt vmcnt(2)" ::: "memory");   // T0 fully landed
  __builtin_amdgcn_s_barrier();

  // ---- main loop: 64 K-tiles (BK=64), 2 per iteration ----
  for (int j = 0; j < 32; ++j) {
    const int k1 = 2*j + 1;
    const int k2 = (2*j + 2 < 64) ? 2*j + 2 : 63;   // clamp: dead-buffer fill
    const int k3 = (2*j + 3 < 64) ? 2*j + 3 : 63;
    PHASE(0, 0, 0, 1, 1, STAGE_B(0, 1, k1), 0);
    PHASE(0, 0, 1, 0, 1, STAGE_B(1, 1, k1), 0);
    PHASE(0, 1, 1, 1, 0, STAGE_A(1, 1, k1), 0);
    PHASE(0, 1, 0, 0, 1, STAGE_A(0, 0, k2), 1);   // vmcnt(2): buf1 ready
    PHASE(1, 0, 0, 1, 1, STAGE_B(0, 0, k2), 0);
    PHASE(1, 0, 1, 0, 1, STAGE_B(1, 0, k2), 0);
    PHASE(1, 1, 1, 1, 0, STAGE_A(1, 0, k2), 0);
    PHASE(1, 1, 0, 0, 1, STAGE_A(0, 1, k3), 1);   // vmcnt(2): buf0 ready
  }
#undef PHASE
#undef STAGE_A
#undef STAGE_B

  // ---- epilogue: C write ----
  const int orow0 = mb*256 + wm*128 + lhalf*4;
  const int ocol0 = nb*256 + wn*64 + lrow;
  #pragma unroll
  for (int m_ = 0; m_ < 8; ++m_)
    #pragma unroll
    for (int n_ = 0; n_ < 4; ++n_)
      #pragma unroll
      for (int q = 0; q < 4; ++q)
        __builtin_nontemporal_store(acc[m_][n_][q],
            &C[(size_t)(orow0 + m_*16 + q)*OUT_DIM + ocol0 + n_*16]);
}

// ---------------- fused persistent kernel: 256 WGs x 512 thr, 1 WG/CU ------
// wg 0-127: recurrence (R12 math, flag at all t) then join ticket loop;
// wg 128-255: gemm consumers from launch. Tile (mb,nb) gated on flag 8mb+7.
__global__ __launch_bounds__(512, 2) void fused_kernel(
    const float* __restrict__ Whh, const float* __restrict__ preT,
    unsigned short* __restrict__ hHi, unsigned short* __restrict__ hLo,
    int* __restrict__ grp, int* __restrict__ rootcnt, int* __restrict__ rootrep,
    int* __restrict__ ticket, const unsigned short* __restrict__ Wmo16,
    float* __restrict__ C) {
  extern __shared__ char smem[];
  __shared__ int tk_ls;
  const int tid = threadIdx.x;
  const int wg  = blockIdx.x;

  if (wg < NWG) {
    // ---- recurrence (LDS overlay: w_lds 96K | red 16.9K | hpk 1K) ----
    unsigned short* w_lds = (unsigned short*)smem;
    float (*red)[16][33] = (float (*)[16][33])(smem + 98304);
    unsigned short (*hpk_hi)[8] = (unsigned short (*)[8])(smem + 115200);
    unsigned short (*hpk_lo)[8] = (unsigned short (*)[8])(smem + 115712);
    const int j0   = wg * 8;
    const int lane = tid & 63;
    const int wv   = tid >> 6;

    for (int s = tid; s < 6144; s += 512) {
      const int ks = s >> 6, l = s & 63;
      const int r = l & 15;
      const int j = j0 + (r & 7);
      const int part = r >> 3;
      const int kb = ks*32 + (l >> 4)*8;
      const float* wp = Whh + (size_t)j*KH + kb;
      unsigned short tmp[8];
      #pragma unroll
      for (int i = 0; i < 8; ++i) {
        const float f = wp[i];
        unsigned short v = bf16_rne(f);
        if (part) v = bf16_rne(f - __uint_as_float((unsigned)v << 16));
        tmp[i] = v;
      }
      *(short8*)&w_lds[s*8] = *(short8*)tmp;
    }
    __syncthreads();

    const short8* wf  = (const short8*)w_lds;
    const short8* hi8 = (const short8*)hHi;
    const short8* lo8 = (const short8*)hLo;

    short8 Rh0[3][4], Rh1[3][4], Rl0[3][4], Rl1[3][4];
    const short8 z8 = {};
    #pragma unroll
    for (int r = 1; r < 3; ++r)
      #pragma unroll
      for (int i = 0; i < 4; ++i) {
        Rh0[r][i] = z8; Rh1[r][i] = z8; Rl0[r][i] = z8; Rl1[r][i] = z8;
      }

    for (int t3 = 0; t3 < 126; t3 += 3) {
      do_step<0,2,1>(t3,   tid, wg, j0, lane, wv, wf, hi8, lo8, preT, hHi, hLo,
                     grp, rootcnt, rootrep, Rh0, Rh1, Rl0, Rl1, red, hpk_hi, hpk_lo);
      do_step<1,0,2>(t3+1, tid, wg, j0, lane, wv, wf, hi8, lo8, preT, hHi, hLo,
                     grp, rootcnt, rootrep, Rh0, Rh1, Rl0, Rl1, red, hpk_hi, hpk_lo);
      do_step<2,1,0>(t3+2, tid, wg, j0, lane, wv, wf, hi8, lo8, preT, hHi, hLo,
                     grp, rootcnt, rootrep, Rh0, Rh1, Rl0, Rl1, red, hpk_hi, hpk_lo);
    }
    do_step<0,2,1>(126, tid, wg, j0, lane, wv, wf, hi8, lo8, preT, hHi, hLo,
                   grp, rootcnt, rootrep, Rh0, Rh1, Rl0, Rl1, red, hpk_hi, hpk_lo);
    do_step<1,0,2>(127, tid, wg, j0, lane, wv, wf, hi8, lo8, preT, hHi, hLo,
                   grp, rootcnt, rootrep, Rh0, Rh1, Rl0, Rl1, red, hpk_hi, hpk_lo);
    __syncthreads();   // all waves out of recur LDS before gemm overlays
  }

  // ---- ticket loop: consume 256x256 tiles as their A windows finalize ----
  for (;;) {
    if (tid == 0)
      tk_ls = __hip_atomic_fetch_add(ticket, 1, __ATOMIC_RELAXED, __HIP_MEMORY_SCOPE_AGENT);
    __syncthreads();
    const int tk = tk_ls;
    __syncthreads();
    if (tk >= NTILE) return;
    const int mb = tk >> 5, nb = tk & 31;
    if (tid == 0) {   // wait for h_{8mb+7} (newest slot of this A window)
      while (!__hip_atomic_load(&rootrep[(((8*mb + 7) << 3) + (wg & 7)) << 4],
                                __ATOMIC_RELAXED, __HIP_MEMORY_SCOPE_AGENT))
        __builtin_amdgcn_s_sleep(2);
    }
    __syncthreads();
    asm volatile("" ::: "memory");
    gemm_tile256(hHi, Wmo16, C, smem, tid, mb, nb);
    __syncthreads();
  }
}

extern "C" void kernel_launch(void* const* d_in, const int* in_sizes, int n_in,
                              void* d_out, int out_size, void* d_ws, size_t ws_size,
                              hipStream_t stream) {
  (void)in_sizes; (void)n_in; (void)out_size; (void)ws_size;
  const float* X   = (const float*)d_in[0];
  const float* Wxh = (const float*)d_in[1];
  const float* Wxb = (const float*)d_in[2];
  const float* Whh = (const float*)d_in[3];
  const float* Wmo = (const float*)d_in[4];
  float* out = (float*)d_out;
  char* ws = (char*)d_ws;

  const size_t OFF_PRET = 0;                                               // 16.8 MB
  const size_t OFF_HHI  = OFF_PRET + (size_t)T_STEPS*H_DIM*BATCH*4;
  const size_t OFF_HLO  = OFF_HHI + (size_t)NSLOT*SLOT_E*2;                // +8.6 MB
  const size_t OFF_GRP  = OFF_HLO + (size_t)NSLOT*SLOT_E*2;                // +8.6 MB
  const size_t OFF_RCNT = OFF_GRP + (size_t)T_STEPS*16*64;                 // +128 KB
  const size_t OFF_RREP = OFF_RCNT + (size_t)T_STEPS*64;                   // +8 KB
  const size_t OFF_TKT  = OFF_RREP + (size_t)T_STEPS*8*64;                 // +64 KB
  const size_t OFF_W16  = OFF_TKT + 64;

  float* preT = (float*)(ws + OFF_PRET);
  unsigned short* hHi = (unsigned short*)(ws + OFF_HHI);
  unsigned short* hLo = (unsigned short*)(ws + OFF_HLO);
  int* grp     = (int*)(ws + OFF_GRP);
  int* rootcnt = (int*)(ws + OFF_RCNT);
  int* rootrep = (int*)(ws + OFF_RREP);
  int* ticket  = (int*)(ws + OFF_TKT);
  unsigned short* Wmo16 = (unsigned short*)(ws + OFF_W16);

  (void)hipFuncSetAttribute(reinterpret_cast<const void*>(fused_kernel),
                            hipFuncAttributeMaxDynamicSharedMemorySize, 131072);

  // zero history slots (128..130), flag lines, ticket
  hipMemsetAsync(hHi + (size_t)128*SLOT_E, 0, (size_t)3*SLOT_E*2, stream);
  hipMemsetAsync(hLo + (size_t)128*SLOT_E, 0, (size_t)3*SLOT_E*2, stream);
  hipMemsetAsync(grp, 0, (size_t)T_STEPS*16*64 + (size_t)T_STEPS*64
                        + (size_t)T_STEPS*8*64 + 64, stream);

  convert_kernel<<<2048, 256, 0, stream>>>(Wmo, Wmo16, (int)((size_t)OUT_DIM*4096/4));
  pre_kernel<<<2048, 256, 0, stream>>>(X, Wxh, Wxb, preT);
  fused_kernel<<<256, 512, 131072, stream>>>(Whh, preT, hHi, hLo, grp, rootcnt,
                                             rootrep, ticket, Wmo16, out);
}

// Round 18
// 1060.082 us; speedup vs baseline: 1.6229x; 1.6229x over previous
//
#include <hip/hip_runtime.h>
#include <hip/hip_bf16.h>

#define T_STEPS 128
#define BATCH   32
#define IN_DIM  512
#define H_DIM   1024
#define OUT_DIM 8192
#define KH      3072   // (K-1)*H
#define NWG     128
#define SLOT_E  32768  // elements per h slot (1024 k * 32 b)
#define NSLOT   131    // h_t stored at slot 127-t; slots 128..130 = zeros

typedef __attribute__((ext_vector_type(8))) short short8;
typedef __attribute__((ext_vector_type(4))) float f32x4;

__device__ __forceinline__ unsigned short bf16_rne(float f) {
  unsigned u = __float_as_uint(f);
  unsigned r = (u + 0x7FFFu + ((u >> 16) & 1u)) >> 16;
  return (unsigned short)r;
}

__device__ __forceinline__ void gload_lds16(const void* g, void* l) {
  __builtin_amdgcn_global_load_lds(
      (const __attribute__((address_space(1))) void*)g,
      (__attribute__((address_space(3))) void*)l, 16, 0, 0);
}

// ---------------- prep: Wmo f32->bf16 (blocks 0-2047) + pre (2048-4095) ----
__global__ __launch_bounds__(256) void prep_kernel(
    const float* __restrict__ Wmo, unsigned short* __restrict__ Wmo16,
    const float* __restrict__ X, const float* __restrict__ Wxh,
    const float* __restrict__ bias, float* __restrict__ preT) {
  const int tid = threadIdx.x;
  const int bid = blockIdx.x;
  if (bid < 2048) {
    // ---- convert: 8192*4096 floats = 8388608 float4 ----
    const int n4 = (int)((size_t)OUT_DIM*4096/4);
    int i = bid * 256 + tid;
    for (; i < n4; i += 2048*256) {
      float4 v = ((const float4*)Wmo)[i];
      ushort4 o;
      o.x = bf16_rne(v.x); o.y = bf16_rne(v.y);
      o.z = bf16_rne(v.z); o.w = bf16_rne(v.w);
      ((ushort4*)Wmo16)[i] = o;
    }
    return;
  }
  // ---- pre[t][j][b] = X@Wxh^T + bias ----
  __shared__ float xs[32][260];
  const int blk = bid - 2048;
  const int t  = blk >> 4;
  const int jb = blk & 15;
  const int b  = tid & 31;
  const int jg = tid >> 5;        // 0..7
  float acc[8];
  #pragma unroll
  for (int i = 0; i < 8; ++i) acc[i] = 0.f;

  for (int kc = 0; kc < 2; ++kc) {
    __syncthreads();
    #pragma unroll
    for (int v = tid; v < 2048; v += 256) {
      int br = v >> 6, i4 = v & 63;
      float4 x4 = *(const float4*)(X + (size_t)t*(BATCH*IN_DIM) + (size_t)br*IN_DIM + kc*256 + i4*4);
      *(float4*)&xs[br][i4*4] = x4;
    }
    __syncthreads();
    for (int i = 0; i < 256; i += 4) {
      const int k = kc*256 + i;
      float4 xv = *(const float4*)&xs[b][i];
      #pragma unroll
      for (int jj = 0; jj < 8; ++jj) {
        const int j = jb*64 + jg + jj*8;
        float4 w4 = *(const float4*)(Wxh + (size_t)j*IN_DIM + k);
        acc[jj] += xv.x*w4.x + xv.y*w4.y + xv.z*w4.z + xv.w*w4.w;
      }
    }
  }
  #pragma unroll
  for (int jj = 0; jj < 8; ++jj) {
    const int j = jb*64 + jg + jj*8;
    preT[(size_t)t*(H_DIM*BATCH) + (size_t)j*BATCH + b] = acc[jj] + bias[j];
  }
}

// ---------------- persistent MFMA recurrence (R12 structure, best: 510us) --
template<int RN, int RD1, int RD2>
__device__ __forceinline__ void do_step(
    const int t, const int tid, const int wg, const int j0,
    const int lane, const int wv,
    const short8* __restrict__ wf, const short8* __restrict__ hi8,
    const short8* __restrict__ lo8, const float* __restrict__ preT,
    unsigned short* __restrict__ hHi, unsigned short* __restrict__ hLo,
    int* __restrict__ grp, int* __restrict__ rootcnt, int* __restrict__ rootrep,
    short8 (&Rh0)[3][4], short8 (&Rh1)[3][4],
    short8 (&Rl0)[3][4], short8 (&Rl1)[3][4],
    float (&red)[8][16][33],
    unsigned short (&hpk_hi)[32][8], unsigned short (&hpk_lo)[32][8]) {
  f32x4 a0h = {}, a0l = {}, a1h = {}, a1l = {};

  // ---- phase A: dk1 + dk2 from registers (no memory) ----
  #pragma unroll
  for (int i = 0; i < 4; ++i) {
    const int ks = 32 + wv*4 + i;
    const short8 af = wf[ks*64 + lane];
    a0h = __builtin_amdgcn_mfma_f32_16x16x32_bf16(af, Rh0[RD1][i], a0h, 0, 0, 0);
    a1h = __builtin_amdgcn_mfma_f32_16x16x32_bf16(af, Rh1[RD1][i], a1h, 0, 0, 0);
    a0l = __builtin_amdgcn_mfma_f32_16x16x32_bf16(af, Rl0[RD1][i], a0l, 0, 0, 0);
    a1l = __builtin_amdgcn_mfma_f32_16x16x32_bf16(af, Rl1[RD1][i], a1l, 0, 0, 0);
  }
  #pragma unroll
  for (int i = 0; i < 4; ++i) {
    const int ks = 64 + wv*4 + i;
    const short8 af = wf[ks*64 + lane];
    a0h = __builtin_amdgcn_mfma_f32_16x16x32_bf16(af, Rh0[RD2][i], a0h, 0, 0, 0);
    a1h = __builtin_amdgcn_mfma_f32_16x16x32_bf16(af, Rh1[RD2][i], a1h, 0, 0, 0);
    a0l = __builtin_amdgcn_mfma_f32_16x16x32_bf16(af, Rl0[RD2][i], a0l, 0, 0, 0);
    a1l = __builtin_amdgcn_mfma_f32_16x16x32_bf16(af, Rl1[RD2][i], a1l, 0, 0, 0);
  }

  // ---- prefetch pre (off the post-reduce critical path) ----
  float upre = 0.f;
  if (tid < 256)
    upre = preT[(size_t)t*(H_DIM*BATCH) + (size_t)(j0 + (tid >> 5))*BATCH + (tid & 31)];

  // ---- wait for h_{t-1}: tid0 polls its replica line, barrier broadcasts --
  if (t > 0) {
    if (tid == 0) {
      while (!__hip_atomic_load(&rootrep[(((t-1) << 3) + (wg & 7)) << 4],
                                __ATOMIC_RELAXED, __HIP_MEMORY_SCOPE_AGENT))
        __builtin_amdgcn_s_sleep(2);
    }
    __syncthreads();
    asm volatile("" ::: "memory");   // no hoisting of slot loads above poll
  }

  // ---- load fresh dk0 slot (h_{t-1}) into set RN ----
  {
    const size_t sb = (size_t)(128 - t) * 4096;   // slot base, 16B units
    #pragma unroll
    for (int i = 0; i < 4; ++i) {
      const int ks = wv*4 + i;
      const size_t bidx = sb + (size_t)ks*128 + (size_t)(lane >> 4)*32 + (lane & 15);
      Rh0[RN][i] = hi8[bidx];
      Rh1[RN][i] = hi8[bidx + 16];
      Rl0[RN][i] = lo8[bidx];
      Rl1[RN][i] = lo8[bidx + 16];
    }
  }
  // ---- phase C: dk0 MFMA ----
  #pragma unroll
  for (int i = 0; i < 4; ++i) {
    const int ks = wv*4 + i;
    const short8 af = wf[ks*64 + lane];
    a0h = __builtin_amdgcn_mfma_f32_16x16x32_bf16(af, Rh0[RN][i], a0h, 0, 0, 0);
    a1h = __builtin_amdgcn_mfma_f32_16x16x32_bf16(af, Rh1[RN][i], a1h, 0, 0, 0);
    a0l = __builtin_amdgcn_mfma_f32_16x16x32_bf16(af, Rl0[RN][i], a0l, 0, 0, 0);
    a1l = __builtin_amdgcn_mfma_f32_16x16x32_bf16(af, Rl1[RN][i], a1l, 0, 0, 0);
  }

  const f32x4 s0 = a0h + a0l;
  const f32x4 s1 = a1h + a1l;
  const int rr = (lane >> 4) * 4, cc = lane & 15;
  #pragma unroll
  for (int q = 0; q < 4; ++q) {
    red[wv][rr + q][cc]      = s0[q];
    red[wv][rr + q][16 + cc] = s1[q];
  }
  __syncthreads();

  if (tid < 256) {
    const int jj = tid >> 5, b = tid & 31;
    float u = upre;
    #pragma unroll
    for (int w = 0; w < 8; ++w)
      u += red[w][jj][b] + red[w][jj + 8][b];
    const float h = u > 0.f ? 1.0507009873554805f*u
                            : (1.0507009873554805f*1.6732632423543772f)*expm1f(u);
    const unsigned short hh = bf16_rne(h);
    hpk_hi[b][jj] = hh;
    hpk_lo[b][jj] = bf16_rne(h - __uint_as_float((unsigned)hh << 16));
  }
  __syncthreads();

  // ---- wave 0: h stores -> ack -> grp -> rootcnt -> 8 replica stores ----
  if (tid < 32) {
    const int b = tid;
    const size_t base = (size_t)(127 - t)*SLOT_E + (size_t)(j0 >> 3)*256 + (size_t)b*8;
    const unsigned long long h0 = *(const unsigned long long*)&hpk_hi[b][0];
    const unsigned long long h1 = *(const unsigned long long*)&hpk_hi[b][4];
    const unsigned long long l0 = *(const unsigned long long*)&hpk_lo[b][0];
    const unsigned long long l1 = *(const unsigned long long*)&hpk_lo[b][4];
    __hip_atomic_store((unsigned long long*)(hHi + base),     h0, __ATOMIC_RELAXED, __HIP_MEMORY_SCOPE_AGENT);
    __hip_atomic_store((unsigned long long*)(hHi + base) + 1, h1, __ATOMIC_RELAXED, __HIP_MEMORY_SCOPE_AGENT);
    __hip_atomic_store((unsigned long long*)(hLo + base),     l0, __ATOMIC_RELAXED, __HIP_MEMORY_SCOPE_AGENT);
    __hip_atomic_store((unsigned long long*)(hLo + base) + 1, l1, __ATOMIC_RELAXED, __HIP_MEMORY_SCOPE_AGENT);
    if (t < T_STEPS - 1) {
      asm volatile("s_waitcnt vmcnt(0)" ::: "memory");   // h visible at L3
      if (tid == 0) {
        const int g = wg >> 3;   // 16 groups of 8 WGs, private 64B lines
        if (__hip_atomic_fetch_add(&grp[((t << 4) + g) << 4], 1, __ATOMIC_RELAXED, __HIP_MEMORY_SCOPE_AGENT) == 7) {
          if (__hip_atomic_fetch_add(&rootcnt[t << 4], 1, __ATOMIC_RELAXED, __HIP_MEMORY_SCOPE_AGENT) == 15) {
            #pragma unroll
            for (int r = 0; r < 8; ++r)
              __hip_atomic_store(&rootrep[((t << 3) + r) << 4], 1,
                                 __ATOMIC_RELAXED, __HIP_MEMORY_SCOPE_AGENT);
          }
        }
      }
    }
  }
  // no barrier: waves proceed into next step's phase A
}

__global__ __launch_bounds__(512, 2) void recur_kernel(
    const float* __restrict__ Whh, const float* __restrict__ preT,
    unsigned short* __restrict__ hHi, unsigned short* __restrict__ hLo,
    int* __restrict__ grp, int* __restrict__ rootcnt, int* __restrict__ rootrep) {
  __shared__ __align__(16) unsigned short w_lds[96*64*8];  // 96 KB A-fragments
  __shared__ float red[8][16][33];
  __shared__ __align__(16) unsigned short hpk_hi[32][8];
  __shared__ __align__(16) unsigned short hpk_lo[32][8];
  const int tid  = threadIdx.x;
  const int wg   = blockIdx.x;
  const int j0   = wg * 8;
  const int lane = tid & 63;
  const int wv   = tid >> 6;       // wave 0..7

  // ---- stage Whh as hi/lo mfma A-fragments (once) ----
  for (int s = tid; s < 6144; s += 512) {
    const int ks = s >> 6, l = s & 63;
    const int r = l & 15;                 // A-row: 0-7 hi, 8-15 lo
    const int j = j0 + (r & 7);
    const int part = r >> 3;
    const int kb = ks*32 + (l >> 4)*8;
    const float* wp = Whh + (size_t)j*KH + kb;
    unsigned short tmp[8];
    #pragma unroll
    for (int i = 0; i < 8; ++i) {
      const float f = wp[i];
      unsigned short v = bf16_rne(f);
      if (part) v = bf16_rne(f - __uint_as_float((unsigned)v << 16));
      tmp[i] = v;
    }
    *(short8*)&w_lds[s*8] = *(short8*)tmp;
  }
  __syncthreads();

  const short8* wf  = (const short8*)w_lds;
  const short8* hi8 = (const short8*)hHi;
  const short8* lo8 = (const short8*)hLo;

  // rotating B-fragment register file: sets 1,2 = zero history
  short8 Rh0[3][4], Rh1[3][4], Rl0[3][4], Rl1[3][4];
  const short8 z8 = {};
  #pragma unroll
  for (int r = 1; r < 3; ++r)
    #pragma unroll
    for (int i = 0; i < 4; ++i) {
      Rh0[r][i] = z8; Rh1[r][i] = z8; Rl0[r][i] = z8; Rl1[r][i] = z8;
    }

  for (int t3 = 0; t3 < 126; t3 += 3) {
    do_step<0,2,1>(t3,   tid, wg, j0, lane, wv, wf, hi8, lo8, preT, hHi, hLo,
                   grp, rootcnt, rootrep, Rh0, Rh1, Rl0, Rl1, red, hpk_hi, hpk_lo);
    do_step<1,0,2>(t3+1, tid, wg, j0, lane, wv, wf, hi8, lo8, preT, hHi, hLo,
                   grp, rootcnt, rootrep, Rh0, Rh1, Rl0, Rl1, red, hpk_hi, hpk_lo);
    do_step<2,1,0>(t3+2, tid, wg, j0, lane, wv, wf, hi8, lo8, preT, hHi, hLo,
                   grp, rootcnt, rootrep, Rh0, Rh1, Rl0, Rl1, red, hpk_hi, hpk_lo);
  }
  do_step<0,2,1>(126, tid, wg, j0, lane, wv, wf, hi8, lo8, preT, hHi, hLo,
                 grp, rootcnt, rootrep, Rh0, Rh1, Rl0, Rl1, red, hpk_hi, hpk_lo);
  do_step<1,0,2>(127, tid, wg, j0, lane, wv, wf, hi8, lo8, preT, hHi, hLo,
                 grp, rootcnt, rootrep, Rh0, Rh1, Rl0, Rl1, red, hpk_hi, hpk_lo);
}

// ---------------- out = hcat @ Wmo16^T : 256x256 8-phase counted-vmcnt -----
// 512 thr (8 waves: wm 0-1 x wn 0-3), BK=64, 128KB dynamic LDS; slot-major
// regions; counted vmcnt(2) at phases 4/8 only; raw s_barrier; setprio MFMA.
// launch_bounds (512,1): LDS already caps at 1 WG/CU; don't constrain regs.
__global__ __launch_bounds__(512, 1) void gemm256_kernel(
    const unsigned short* __restrict__ Ah, const unsigned short* __restrict__ Bm,
    float* __restrict__ C) {
  extern __shared__ char smem[];
  const int tid = threadIdx.x;
  const int wg = blockIdx.x;
  // XCD-chunked: XCD x owns nb x*4..x*4+3; mb fastest (B panel L2-resident)
  const int x = wg & 7;
  const int c = wg >> 3;
  const int mb = c & 15;                 // 16 mb tiles (M=4096)
  const int nb = x*4 + (c >> 4);         // 32 nb tiles (N=8192)
  const int lane = tid & 63;
  const int wv = tid >> 6;
  const int wm = wv >> 2;                // 0..1 -> rows wm*128..+127
  const int wn = wv & 3;                 // 0..3 -> cols wn*64..+63
  const int lrow = lane & 15, lhalf = lane >> 4;
  // staging map: thread -> (row = tid&127, slot = u*4 + (tid>>7))
  const int srow = tid & 127;
  const int ss0 = tid >> 7;
  int tA[2], bA[2];
  #pragma unroll
  for (int h = 0; h < 2; ++h) {
    const int m = mb*256 + h*128 + srow;
    tA[h] = m >> 5; bA[h] = m & 31;
  }

#define STAGE_A(HALF, BUF, KT) do {                                            \
    _Pragma("unroll")                                                          \
    for (int u = 0; u < 2; ++u) {                                              \
      const int s_ = u*4 + ss0;                                                \
      gload_lds16(Ah + (size_t)(127 - tA[HALF])*SLOT_E                         \
                     + (size_t)((KT)*8 + s_)*256 + bA[HALF]*8,                 \
                  smem + (BUF)*65536 + (HALF)*16384 + u*8192 + tid*16);        \
    } } while (0)

#define STAGE_B(HALF, BUF, KT) do {                                            \
    _Pragma("unroll")                                                          \
    for (int u = 0; u < 2; ++u) {                                              \
      const int s_ = u*4 + ss0;                                                \
      gload_lds16(Bm + (size_t)(nb*256 + (HALF)*128 + srow)*4096               \
                     + (size_t)(KT)*64 + s_*8,                                 \
                  smem + (BUF)*65536 + 32768 + (HALF)*16384 + u*8192 + tid*16);\
    } } while (0)

  short8 aF[4][2], bF[2][2];
  f32x4 acc[8][4] = {};

#define PHASE(BUF, MH, NH, RDA, RDB, STAGE_STMT, DO_VM) do {                   \
    if (RDA) {                                                                 \
      _Pragma("unroll")                                                        \
      for (int mi = 0; mi < 4; ++mi)                                           \
        _Pragma("unroll")                                                      \
        for (int kk = 0; kk < 2; ++kk)                                         \
          aF[mi][kk] = *(const short8*)(smem + (BUF)*65536 + wm*16384          \
              + (kk*4 + lhalf)*2048 + ((MH)*64 + mi*16 + lrow)*16);            \
    }                                                                          \
    if (RDB) {                                                                 \
      _Pragma("unroll")                                                        \
      for (int ni = 0; ni < 2; ++ni)                                           \
        _Pragma("unroll")                                                      \
        for (int kk = 0; kk < 2; ++kk)                                         \
          bF[ni][kk] = *(const short8*)(smem + (BUF)*65536 + 32768             \
              + (wn >> 1)*16384 + (kk*4 + lhalf)*2048                          \
              + ((wn & 1)*64 + (NH)*32 + ni*16 + lrow)*16);                    \
    }                                                                          \
    STAGE_STMT;                                                                \
    __builtin_amdgcn_s_barrier();                                              \
    __builtin_amdgcn_s_setprio(1);                                             \
    _Pragma("unroll")                                                          \
    for (int mi = 0; mi < 4; ++mi)                                             \
      _Pragma("unroll")                                                        \
      for (int ni = 0; ni < 2; ++ni) {                                         \
        acc[(MH)*4+mi][(NH)*2+ni] = __builtin_amdgcn_mfma_f32_16x16x32_bf16(   \
            aF[mi][0], bF[ni][0], acc[(MH)*4+mi][(NH)*2+ni], 0, 0, 0);         \
        acc[(MH)*4+mi][(NH)*2+ni] = __builtin_amdgcn_mfma_f32_16x16x32_bf16(   \
            aF[mi][1], bF[ni][1], acc[(MH)*4+mi][(NH)*2+ni], 0, 0, 0);         \
      }                                                                        \
    __builtin_amdgcn_s_setprio(0);                                             \
    if (DO_VM) asm volatile("s_waitcnt vmcnt(2)" ::: "memory");                \
    __builtin_amdgcn_s_barrier();                                              \
  } while (0)

  // ---- prologue: T0 -> buf0 (4 half-tiles), Ah0(T1) -> buf1 ----
  STAGE_A(0, 0, 0);
  STAGE_B(0, 0, 0);
  STAGE_B(1, 0, 0);
  STAGE_A(1, 0, 0);
  STAGE_A(0, 1, 1);
  asm volatile("s_waitcnt vmcnt(2)" ::: "memory");   // T0 fully landed
  __builtin_amdgcn_s_barrier();

  // ---- main loop: 64 K-tiles (BK=64), 2 per iteration ----
  for (int j = 0; j < 32; ++j) {
    const int k1 = 2*j + 1;
    const int k2 = (2*j + 2 < 64) ? 2*j + 2 : 63;   // clamp: dead-buffer fill
    const int k3 = (2*j + 3 < 64) ? 2*j + 3 : 63;
    PHASE(0, 0, 0, 1, 1, STAGE_B(0, 1, k1), 0);
    PHASE(0, 0, 1, 0, 1, STAGE_B(1, 1, k1), 0);
    PHASE(0, 1, 1, 1, 0, STAGE_A(1, 1, k1), 0);
    PHASE(0, 1, 0, 0, 1, STAGE_A(0, 0, k2), 1);   // vmcnt(2): buf1 ready
    PHASE(1, 0, 0, 1, 1, STAGE_B(0, 0, k2), 0);
    PHASE(1, 0, 1, 0, 1, STAGE_B(1, 0, k2), 0);
    PHASE(1, 1, 1, 1, 0, STAGE_A(1, 0, k2), 0);
    PHASE(1, 1, 0, 0, 1, STAGE_A(0, 1, k3), 1);   // vmcnt(2): buf0 ready
  }
#undef PHASE
#undef STAGE_A
#undef STAGE_B

  // ---- epilogue: C write ----
  const int orow0 = mb*256 + wm*128 + lhalf*4;
  const int ocol0 = nb*256 + wn*64 + lrow;
  #pragma unroll
  for (int m_ = 0; m_ < 8; ++m_)
    #pragma unroll
    for (int n_ = 0; n_ < 4; ++n_)
      #pragma unroll
      for (int q = 0; q < 4; ++q)
        __builtin_nontemporal_store(acc[m_][n_][q],
            &C[(size_t)(orow0 + m_*16 + q)*OUT_DIM + ocol0 + n_*16]);
}

extern "C" void kernel_launch(void* const* d_in, const int* in_sizes, int n_in,
                              void* d_out, int out_size, void* d_ws, size_t ws_size,
                              hipStream_t stream) {
  (void)in_sizes; (void)n_in; (void)out_size; (void)ws_size;
  const float* X   = (const float*)d_in[0];
  const float* Wxh = (const float*)d_in[1];
  const float* Wxb = (const float*)d_in[2];
  const float* Whh = (const float*)d_in[3];
  const float* Wmo = (const float*)d_in[4];
  float* out = (float*)d_out;
  char* ws = (char*)d_ws;

  const size_t OFF_PRET = 0;                                               // 16.8 MB
  const size_t OFF_HHI  = OFF_PRET + (size_t)T_STEPS*H_DIM*BATCH*4;
  const size_t OFF_HLO  = OFF_HHI + (size_t)NSLOT*SLOT_E*2;                // +8.6 MB
  const size_t OFF_GRP  = OFF_HLO + (size_t)NSLOT*SLOT_E*2;                // +8.6 MB
  const size_t OFF_RCNT = OFF_GRP + (size_t)T_STEPS*16*64;                 // +128 KB
  const size_t OFF_RREP = OFF_RCNT + (size_t)T_STEPS*64;                   // +8 KB
  const size_t OFF_W16  = OFF_RREP + (size_t)T_STEPS*8*64;                 // +64 KB

  float* preT = (float*)(ws + OFF_PRET);
  unsigned short* hHi = (unsigned short*)(ws + OFF_HHI);
  unsigned short* hLo = (unsigned short*)(ws + OFF_HLO);
  int* grp     = (int*)(ws + OFF_GRP);
  int* rootcnt = (int*)(ws + OFF_RCNT);
  int* rootrep = (int*)(ws + OFF_RREP);
  unsigned short* Wmo16 = (unsigned short*)(ws + OFF_W16);

  (void)hipFuncSetAttribute(reinterpret_cast<const void*>(gemm256_kernel),
                            hipFuncAttributeMaxDynamicSharedMemorySize, 131072);

  // zero history slots (128..130) and all flag lines
  hipMemsetAsync(hHi + (size_t)128*SLOT_E, 0, (size_t)3*SLOT_E*2, stream);
  hipMemsetAsync(hLo + (size_t)128*SLOT_E, 0, (size_t)3*SLOT_E*2, stream);
  hipMemsetAsync(grp, 0, (size_t)T_STEPS*16*64 + (size_t)T_STEPS*64
                        + (size_t)T_STEPS*8*64, stream);

  prep_kernel<<<4096, 256, 0, stream>>>(Wmo, Wmo16, X, Wxh, Wxb, preT);
  recur_kernel<<<NWG, 512, 0, stream>>>(Whh, preT, hHi, hLo, grp, rootcnt, rootrep);
  gemm256_kernel<<<512, 512, 131072, stream>>>(hHi, Wmo16, out);
}